// Round 2
// baseline (281.221 us; speedup 1.0000x reference)
//
#include <hip/hip_runtime.h>
#include <math.h>

#define MEMSZ 16384
#define NCTX  16453   // MEM + 5 + 64
#define MAXT  16      // fast-path unroll bound (num_steps in harness = 16)
#define LOGCAP 64     // ws log stride per row (supports T<=64 via seq path)

// ---- soft-gate helpers (exact float32 replication of the reference) ----
__device__ __forceinline__ float sigmoidf_(float x) {
    return 1.0f / (1.0f + __expf(-x));
}
__device__ __forceinline__ float siluf_(float x) {
    return x * sigmoidf_(x);
}
__device__ __forceinline__ float silu_thr(float x) {
    float d = 20.0f * x;
    return (siluf_(d + 10.0f) - siluf_(d - 10.0f)) * 0.05f;
}
__device__ __forceinline__ float eq_gate_d(float diff) {
    return silu_thr(diff + 0.5f) * silu_thr(0.5f - diff);
}

__device__ __forceinline__ float clipaddr(float x) {
    return fminf(fmaxf(x, 0.0f), (float)(NCTX - 1));
}

// register/context value for slot r = ai - MEMSZ (r in [0,68])
__device__ __forceinline__ float regval(int r, float pcv, float spv, float bpv,
                                        float axv, float olf,
                                        const float* __restrict__ orow) {
    return (r == 0) ? pcv
         : (r == 1) ? spv
         : (r == 2) ? bpv
         : (r == 3) ? axv
         : (r == 4) ? olf
                    : orow[r - 5];
}

__device__ __forceinline__ float pop_of(float opc) {
    const float opv[15] = {1.f, 2.f, 9.f, 10.f, 11.f, 12.f, 13.f, 14.f, 15.f,
                           3.f, 4.f, 5.f, 6.f, 7.f, 8.f};
    float pop = 0.0f;
#pragma unroll
    for (int j = 0; j < 15; ++j) {
        float g = eq_gate_d(opc - opv[j]);
        if (j >= 2) pop += g;
    }
    return pop;
}

// experts + gates; returns new_ax, writes pop gate sum
__device__ __forceinline__ float step_update(float stv, float ax, float imm,
                                             float bp, float opc, float* pop_out) {
    const float opv[15] = {1.f, 2.f, 9.f, 10.f, 11.f, 12.f, 13.f, 14.f, 15.f,
                           3.f, 4.f, 5.f, 6.f, 7.f, 8.f};
    float a = stv, bv = ax;
    float safeb = (fabsf(bv) < 1e-6f) ? 1e-6f : bv;
    float dv = a / safeb;
    float md = a - safeb * floorf(dv);
    float sh = fminf(fmaxf(bv, 0.0f), 31.0f);
    float eq = eq_gate_d(a - bv);
    float lt = sigmoidf_(20.0f * (bv - a - 0.5f));
    float gt = sigmoidf_(20.0f * (a - bv - 0.5f));
    float outs[15] = {
        imm, bp + imm, a + bv, a - bv, a * bv, dv, md,
        a * exp2f(sh), a * exp2f(-sh),
        eq, 1.0f - eq, lt, gt, 1.0f - gt, 1.0f - lt
    };
    float gsum = 0.0f, acc = 0.0f, pop = 0.0f;
#pragma unroll
    for (int j = 0; j < 15; ++j) {
        float g = eq_gate_d(opc - opv[j]);
        gsum += g;
        acc += g * outs[j];
        if (j >= 2) pop += g;
    }
    *pop_out = pop;
    return acc + (1.0f - gsum) * ax;
}

// ---- fused: bulk copy (blocks [0,copyBlocks)) + per-row sim (rest) ----
// Sim reads PRISTINE input memory and emits a (target,val) write-log to ws.
// ws layout: la[B*LOGCAP] ints, then lv[B*LOGCAP] floats (512 KB @ B=1024).
__global__ void copy_sim_kernel(const float* __restrict__ mem,
                                float* __restrict__ out,
                                const float* __restrict__ outp,
                                const float* __restrict__ ax_in,
                                const int* __restrict__ pc_in,
                                const int* __restrict__ sp_in,
                                const int* __restrict__ bp_in,
                                const int* __restrict__ ol_in,
                                const int* __restrict__ nstep,
                                int B, int copyBlocks,
                                int* la, float* lv) {
    int blk = blockIdx.x;
    int tid = threadIdx.x;

    if (blk < copyBlocks) {
        // grid-stride float4 copy, 8 x 16B per thread
        const float4* s = (const float4*)mem;
        float4* d = (float4*)out;
        long n4 = (long)B * MEMSZ / 4;
        long i = (long)blk * 256 + tid;
        long stride = (long)copyBlocks * 256;
#pragma unroll
        for (int k = 0; k < 8; ++k) {
            long idx = i + (long)k * stride;
            if (idx < n4) d[idx] = s[idx];
        }
        return;
    }

    int b = (blk - copyBlocks) * blockDim.x + tid;
    if (b >= B) return;

    const float* __restrict__ mrow = mem + (size_t)b * MEMSZ;
    const float* __restrict__ orow = outp + (size_t)b * 64;
    int*   lrow_a = la + (size_t)b * LOGCAP;
    float* lrow_v = lv + (size_t)b * LOGCAP;

    float pc0 = (float)pc_in[b];
    float sp0 = (float)sp_in[b];
    float bp0 = (float)bp_in[b];
    float ax0 = ax_in[b];
    float olf = (float)ol_in[b];
    int T = nstep[0];

    bool slow = (T > MAXT) || (T < 0);
    float rawv[MAXT];   // prefetched instruction loads
    float spA[MAXT];    // sp at start of each step
    int   tgt[MAXT];    // scatter target (memory index) per step
    float svr[MAXT];    // prefetched stack-top raw loads
    float lvv[MAXT];    // written values (log)

    if (!slow) {
        // prefetch all instruction loads (pc chain is static)
#pragma unroll
        for (int t = 0; t < MAXT; ++t) {
            if (t < T) {
                int ai = (int)clipaddr(pc0 + 8.0f * t);
                int ia = (ai < MEMSZ) ? ai : ai - MEMSZ;
                rawv[t] = mrow[ia];
            }
        }
        // pass A: opcode -> pop -> sp chain -> targets (ALU only)
        float spc = sp0;
#pragma unroll
        for (int t = 0; t < MAXT; ++t) {
            if (t >= T) break;
            int ai = (int)clipaddr(pc0 + 8.0f * t);
            int ia = (ai < MEMSZ) ? ai : ai - MEMSZ;
#pragma unroll
            for (int j = 0; j < MAXT; ++j)
                if (j < t && tgt[j] == ia) slow = true;  // RAW hazard on inst
            float inst;
            if (ai < MEMSZ) {
                inst = rawv[t];
            } else {
                int r = ai - MEMSZ;
                if (r == 3) slow = true;                 // needs ax chain
                float cv = regval(r, pc0 + 8.0f * t, spc, bp0, 0.0f, olf, orow);
                inst = 0.5f * (cv + rawv[t]);
            }
            float imm = floorf(inst * (1.0f / 256.0f));
            float opc = inst - imm * 256.0f;
            float popv = pop_of(opc);
            spA[t] = spc;
            int si = (int)clipaddr(spc);
            tgt[t] = (si < MEMSZ) ? si : si - MEMSZ;
            spc = spc + 8.0f * popv;
        }
    }

    if (!slow) {
        // pass B: all stack-top loads in parallel
#pragma unroll
        for (int t = 0; t < MAXT; ++t)
            if (t < T) svr[t] = mrow[tgt[t]];
        // pass C: ax chain + experts + write-log (ALU only)
        float ax = ax0;
#pragma unroll
        for (int t = 0; t < MAXT; ++t) {
            if (t >= T) break;
            int ai = (int)clipaddr(pc0 + 8.0f * t);
            float inst;
            if (ai < MEMSZ) {
                inst = rawv[t];
            } else {
                int r = ai - MEMSZ;
                float cv = regval(r, pc0 + 8.0f * t, spA[t], bp0, ax, olf, orow);
                inst = 0.5f * (cv + rawv[t]);
            }
            float imm = floorf(inst * (1.0f / 256.0f));
            float opc = inst - imm * 256.0f;
            float mtv = svr[t];
            int tg = tgt[t];
#pragma unroll
            for (int j = 0; j < MAXT; ++j)
                if (j < t && tgt[j] == tg) mtv = lvv[j];  // overlay: last write wins
            int si = (int)clipaddr(spA[t]);
            float stv, wf;
            if (si < MEMSZ) {
                stv = mtv; wf = 1.0f;
            } else {
                int r = si - MEMSZ;
                float cv = regval(r, pc0 + 8.0f * t, spA[t], bp0, ax, olf, orow);
                stv = 0.5f * (cv + mtv); wf = 0.5f;
            }
            float pop;
            float nax = step_update(stv, ax, imm, bp0, opc, &pop);
            lvv[t] = mtv + pop * wf * (nax - mtv);
            ax = nax;
        }
        // dump log to ws
#pragma unroll
        for (int t = 0; t < MAXT; ++t)
            if (t < T) { lrow_a[t] = tgt[t]; lrow_v[t] = lvv[t]; }
    } else {
        // generic fully-sequential path (hazard rows / T > MAXT), ws-based log
        float pc = pc0, sp = sp0, ax = ax0;
        int Tc = (T > LOGCAP) ? LOGCAP : T;
        for (int t = 0; t < Tc; ++t) {
            int ai = (int)clipaddr(pc);
            int ia = (ai < MEMSZ) ? ai : ai - MEMSZ;
            float v = mrow[ia];
            for (int j = 0; j < t; ++j)
                if (lrow_a[j] == ia) v = lrow_v[j];
            float inst;
            if (ai < MEMSZ) {
                inst = v;
            } else {
                int r = ai - MEMSZ;
                float cv = regval(r, pc, sp, bp0, ax, olf, orow);
                inst = 0.5f * (cv + v);
            }
            float imm = floorf(inst * (1.0f / 256.0f));
            float opc = inst - imm * 256.0f;
            int si = (int)clipaddr(sp);
            int tg = (si < MEMSZ) ? si : si - MEMSZ;
            float mtv = mrow[tg];
            for (int j = 0; j < t; ++j)
                if (lrow_a[j] == tg) mtv = lrow_v[j];
            float stv, wf;
            if (si < MEMSZ) {
                stv = mtv; wf = 1.0f;
            } else {
                int r = si - MEMSZ;
                float cv = regval(r, pc, sp, bp0, ax, olf, orow);
                stv = 0.5f * (cv + mtv); wf = 0.5f;
            }
            float pop;
            float nax = step_update(stv, ax, imm, bp0, opc, &pop);
            float val = mtv + pop * wf * (nax - mtv);
            lrow_a[t] = tg;
            lrow_v[t] = val;
            sp = sp + 8.0f * pop;
            pc = pc + 8.0f;
            ax = nax;
        }
    }
}

// ---- apply the write-log onto the copied memory (last write wins) ----
__global__ void apply_kernel(float* __restrict__ out,
                             const int* __restrict__ la,
                             const float* __restrict__ lv,
                             const int* __restrict__ nstep, int B) {
    int row = blockIdx.x;
    int tid = threadIdx.x;
    int T = nstep[0];
    if (T > LOGCAP) T = LOGCAP;
    __shared__ int sla[LOGCAP];
    if (tid < LOGCAP) sla[tid] = (tid < T) ? la[(size_t)row * LOGCAP + tid] : -1;
    __syncthreads();
    if (tid < T) {
        int a = sla[tid];
        bool last = true;
        for (int j = tid + 1; j < T; ++j)
            if (sla[j] == a) last = false;
        if (last)
            out[(size_t)row * MEMSZ + a] = lv[(size_t)row * LOGCAP + tid];
    }
}

extern "C" void kernel_launch(void* const* d_in, const int* in_sizes, int n_in,
                              void* d_out, int out_size, void* d_ws, size_t ws_size,
                              hipStream_t stream) {
    const float* memory = (const float*)d_in[0];
    const float* output = (const float*)d_in[1];
    const float* ax     = (const float*)d_in[2];
    const int*   pc     = (const int*)d_in[3];
    const int*   sp     = (const int*)d_in[4];
    const int*   bp     = (const int*)d_in[5];
    const int*   ol     = (const int*)d_in[6];
    const int*   ns     = (const int*)d_in[7];

    int B = in_sizes[0] / MEMSZ;
    long n4 = (long)B * MEMSZ / 4;
    int copyBlocks = (int)((n4 + 256 * 8 - 1) / (256 * 8));
    int simBlocks = (B + 255) / 256;

    float* out = (float*)d_out;
    // ws log: la[B*LOGCAP] ints then lv[B*LOGCAP] floats (512 KB @ B=1024)
    int* la = (int*)d_ws;
    float* lv = (float*)(la + (size_t)B * LOGCAP);

    hipLaunchKernelGGL(copy_sim_kernel, dim3(copyBlocks + simBlocks), dim3(256), 0, stream,
                       memory, out, output, ax, pc, sp, bp, ol, ns,
                       B, copyBlocks, la, lv);
    hipLaunchKernelGGL(apply_kernel, dim3(B), dim3(64), 0, stream,
                       out, la, lv, ns, B);
}

// Round 3
// 270.712 us; speedup vs baseline: 1.0388x; 1.0388x over previous
//
#include <hip/hip_runtime.h>
#include <math.h>

#define MEMSZ 16384
#define NCTX  16453   // MEM + 5 + 64
#define MAXT  16      // fast-path unroll bound (num_steps in harness = 16)
#define LOGCAP 64     // ws log stride per row (slow path supports T<=64)

// ---- soft-gate helpers (exact float32 replication of the reference) ----
__device__ __forceinline__ float sigmoidf_(float x) {
    return 1.0f / (1.0f + __expf(-x));
}
__device__ __forceinline__ float siluf_(float x) {
    return x * sigmoidf_(x);
}
__device__ __forceinline__ float silu_thr(float x) {
    float d = 20.0f * x;
    return (siluf_(d + 10.0f) - siluf_(d - 10.0f)) * 0.05f;
}
__device__ __forceinline__ float eq_gate_d(float diff) {
    return silu_thr(diff + 0.5f) * silu_thr(0.5f - diff);
}

__device__ __forceinline__ float clipaddr(float x) {
    return fminf(fmaxf(x, 0.0f), (float)(NCTX - 1));
}

// register/context value for slot r = ai - MEMSZ (r in [0,68])
__device__ __forceinline__ float regval(int r, float pcv, float spv, float bpv,
                                        float axv, float olf,
                                        const float* __restrict__ orow) {
    return (r == 0) ? pcv
         : (r == 1) ? spv
         : (r == 2) ? bpv
         : (r == 3) ? axv
         : (r == 4) ? olf
                    : orow[r - 5];
}

__device__ __forceinline__ float pop_of(float opc) {
    const float opv[15] = {1.f, 2.f, 9.f, 10.f, 11.f, 12.f, 13.f, 14.f, 15.f,
                           3.f, 4.f, 5.f, 6.f, 7.f, 8.f};
    float pop = 0.0f;
#pragma unroll
    for (int j = 0; j < 15; ++j) {
        float g = eq_gate_d(opc - opv[j]);
        if (j >= 2) pop += g;
    }
    return pop;
}

// experts + gates; returns new_ax, writes pop gate sum
__device__ __forceinline__ float step_update(float stv, float ax, float imm,
                                             float bp, float opc, float* pop_out) {
    const float opv[15] = {1.f, 2.f, 9.f, 10.f, 11.f, 12.f, 13.f, 14.f, 15.f,
                           3.f, 4.f, 5.f, 6.f, 7.f, 8.f};
    float a = stv, bv = ax;
    float safeb = (fabsf(bv) < 1e-6f) ? 1e-6f : bv;
    float dv = a / safeb;
    float md = a - safeb * floorf(dv);
    float sh = fminf(fmaxf(bv, 0.0f), 31.0f);
    float eq = eq_gate_d(a - bv);
    float lt = sigmoidf_(20.0f * (bv - a - 0.5f));
    float gt = sigmoidf_(20.0f * (a - bv - 0.5f));
    float outs[15] = {
        imm, bp + imm, a + bv, a - bv, a * bv, dv, md,
        a * exp2f(sh), a * exp2f(-sh),
        eq, 1.0f - eq, lt, gt, 1.0f - gt, 1.0f - lt
    };
    float gsum = 0.0f, acc = 0.0f, pop = 0.0f;
#pragma unroll
    for (int j = 0; j < 15; ++j) {
        float g = eq_gate_d(opc - opv[j]);
        gsum += g;
        acc += g * outs[j];
        if (j >= 2) pop += g;
    }
    *pop_out = pop;
    return acc + (1.0f - gsum) * ax;
}

// ---- bulk copy: memory -> d_out ----
__global__ void copy_kernel(const float4* __restrict__ src,
                            float4* __restrict__ dst, int n4) {
    int i = blockIdx.x * blockDim.x + threadIdx.x;
    if (i < n4) dst[i] = src[i];
}

// ---- per-row sim: reads PRISTINE input mem, writes results into out ----
// Runs AFTER copy. One thread per row; direct in-order stores to out give
// last-write-wins for free. 64-thread blocks + launch_bounds(64,1) so the
// ~80 register-array slots do NOT spill (round-2 regression: VGPR=60 spill).
__global__ void __launch_bounds__(64, 1)
sim_kernel(const float* __restrict__ mem,
           float* __restrict__ out,
           const float* __restrict__ outp,
           const float* __restrict__ ax_in,
           const int* __restrict__ pc_in,
           const int* __restrict__ sp_in,
           const int* __restrict__ bp_in,
           const int* __restrict__ ol_in,
           const int* __restrict__ nstep,
           int B, int* la, float* lv) {
    int b = blockIdx.x * blockDim.x + threadIdx.x;
    if (b >= B) return;

    const float* __restrict__ mrow = mem + (size_t)b * MEMSZ;
    float* __restrict__ wrow = out + (size_t)b * MEMSZ;
    const float* __restrict__ orow = outp + (size_t)b * 64;

    float pc0 = (float)pc_in[b];
    float sp0 = (float)sp_in[b];
    float bp0 = (float)bp_in[b];
    float ax0 = ax_in[b];
    float olf = (float)ol_in[b];
    int T = nstep[0];

    bool slow = (T > MAXT) || (T < 0);
    float rawv[MAXT];   // prefetched instruction loads
    float spA[MAXT];    // sp at start of each step
    int   tgt[MAXT];    // scatter target (memory index) per step
    float svr[MAXT];    // prefetched stack-top raw loads
    float lvv[MAXT];    // written values (overlay log)

    if (!slow) {
        // prefetch all instruction loads (pc chain is static)
#pragma unroll
        for (int t = 0; t < MAXT; ++t) {
            if (t < T) {
                int ai = (int)clipaddr(pc0 + 8.0f * t);
                int ia = (ai < MEMSZ) ? ai : ai - MEMSZ;
                rawv[t] = mrow[ia];
            }
        }
        // pass A: opcode -> pop -> sp chain -> targets (ALU only)
        float spc = sp0;
#pragma unroll
        for (int t = 0; t < MAXT; ++t) {
            if (t >= T) break;
            int ai = (int)clipaddr(pc0 + 8.0f * t);
            int ia = (ai < MEMSZ) ? ai : ai - MEMSZ;
#pragma unroll
            for (int j = 0; j < MAXT; ++j)
                if (j < t && tgt[j] == ia) slow = true;  // RAW hazard on inst
            float inst;
            if (ai < MEMSZ) {
                inst = rawv[t];
            } else {
                int r = ai - MEMSZ;
                if (r == 3) slow = true;                 // needs ax chain
                float cv = regval(r, pc0 + 8.0f * t, spc, bp0, 0.0f, olf, orow);
                inst = 0.5f * (cv + rawv[t]);
            }
            float imm = floorf(inst * (1.0f / 256.0f));
            float opc = inst - imm * 256.0f;
            float popv = pop_of(opc);
            spA[t] = spc;
            int si = (int)clipaddr(spc);
            tgt[t] = (si < MEMSZ) ? si : si - MEMSZ;
            spc = spc + 8.0f * popv;
        }
    }

    if (!slow) {
        // pass B: all stack-top loads in parallel
#pragma unroll
        for (int t = 0; t < MAXT; ++t)
            if (t < T) svr[t] = mrow[tgt[t]];
        // pass C: ax chain + experts + direct in-order writes (ALU only)
        float ax = ax0;
#pragma unroll
        for (int t = 0; t < MAXT; ++t) {
            if (t >= T) break;
            int ai = (int)clipaddr(pc0 + 8.0f * t);
            float inst;
            if (ai < MEMSZ) {
                inst = rawv[t];
            } else {
                int r = ai - MEMSZ;
                float cv = regval(r, pc0 + 8.0f * t, spA[t], bp0, ax, olf, orow);
                inst = 0.5f * (cv + rawv[t]);
            }
            float imm = floorf(inst * (1.0f / 256.0f));
            float opc = inst - imm * 256.0f;
            float mtv = svr[t];
            int tg = tgt[t];
#pragma unroll
            for (int j = 0; j < MAXT; ++j)
                if (j < t && tgt[j] == tg) mtv = lvv[j];  // overlay: last write wins
            int si = (int)clipaddr(spA[t]);
            float stv, wf;
            if (si < MEMSZ) {
                stv = mtv; wf = 1.0f;
            } else {
                int r = si - MEMSZ;
                float cv = regval(r, pc0 + 8.0f * t, spA[t], bp0, ax, olf, orow);
                stv = 0.5f * (cv + mtv); wf = 0.5f;
            }
            float pop;
            float nax = step_update(stv, ax, imm, bp0, opc, &pop);
            float val = mtv + pop * wf * (nax - mtv);
            lvv[t] = val;
            wrow[tg] = val;        // in-order per-thread stores: last write wins
            ax = nax;
        }
    } else {
        // generic fully-sequential path (hazard rows / T > MAXT), ws-based log
        int*   lrow_a = la + (size_t)b * LOGCAP;
        float* lrow_v = lv + (size_t)b * LOGCAP;
        float pc = pc0, sp = sp0, ax = ax0;
        int Tc = (T > LOGCAP) ? LOGCAP : T;
        for (int t = 0; t < Tc; ++t) {
            int ai = (int)clipaddr(pc);
            int ia = (ai < MEMSZ) ? ai : ai - MEMSZ;
            float v = mrow[ia];
            for (int j = 0; j < t; ++j)
                if (lrow_a[j] == ia) v = lrow_v[j];
            float inst;
            if (ai < MEMSZ) {
                inst = v;
            } else {
                int r = ai - MEMSZ;
                float cv = regval(r, pc, sp, bp0, ax, olf, orow);
                inst = 0.5f * (cv + v);
            }
            float imm = floorf(inst * (1.0f / 256.0f));
            float opc = inst - imm * 256.0f;
            int si = (int)clipaddr(sp);
            int tg = (si < MEMSZ) ? si : si - MEMSZ;
            float mtv = mrow[tg];
            for (int j = 0; j < t; ++j)
                if (lrow_a[j] == tg) mtv = lrow_v[j];
            float stv, wf;
            if (si < MEMSZ) {
                stv = mtv; wf = 1.0f;
            } else {
                int r = si - MEMSZ;
                float cv = regval(r, pc, sp, bp0, ax, olf, orow);
                stv = 0.5f * (cv + mtv); wf = 0.5f;
            }
            float pop;
            float nax = step_update(stv, ax, imm, bp0, opc, &pop);
            float val = mtv + pop * wf * (nax - mtv);
            lrow_a[t] = tg;
            lrow_v[t] = val;
            wrow[tg] = val;        // in-order per-thread stores: last write wins
            sp = sp + 8.0f * pop;
            pc = pc + 8.0f;
            ax = nax;
        }
    }
}

extern "C" void kernel_launch(void* const* d_in, const int* in_sizes, int n_in,
                              void* d_out, int out_size, void* d_ws, size_t ws_size,
                              hipStream_t stream) {
    const float* memory = (const float*)d_in[0];
    const float* output = (const float*)d_in[1];
    const float* ax     = (const float*)d_in[2];
    const int*   pc     = (const int*)d_in[3];
    const int*   sp     = (const int*)d_in[4];
    const int*   bp     = (const int*)d_in[5];
    const int*   ol     = (const int*)d_in[6];
    const int*   ns     = (const int*)d_in[7];

    int B = in_sizes[0] / MEMSZ;
    int n4 = B * MEMSZ / 4;

    float* out = (float*)d_out;
    int* la = (int*)d_ws;
    float* lv = (float*)(la + (size_t)B * LOGCAP);

    hipLaunchKernelGGL(copy_kernel, dim3((n4 + 255) / 256), dim3(256), 0, stream,
                       (const float4*)memory, (float4*)out, n4);
    hipLaunchKernelGGL(sim_kernel, dim3((B + 63) / 64), dim3(64), 0, stream,
                       memory, out, output, ax, pc, sp, bp, ol, ns, B, la, lv);
}